// Round 13
// baseline (1218.820 us; speedup 1.0000x reference)
//
#include <hip/hip_runtime.h>
#include <hip/hip_bf16.h>
#include <math.h>

// Problem constants (match reference)
#define BB 4
#define PP 32768
#define TOPK 5000
#define NB 4096
#define NBK 20
#define TBPI 210         // NBK*(NBK+1)/2 triangular tile pairs
#define BMW 160          // bitmap words per (full) row
#define TRIW 411872u     // packed triangular bitmap words per image

// ws layout (bytes). End 3,695,232 <= 3,742,720 proven available.
// TWO packed bitmaps alias the dead phase-1 buffers.
#define NV_OFF     0u
#define NC_OFF     64u
#define CS_OFF     256u         // float[BB*TOPK]  = 80,000
#define CB_OFF     80256u       // float4[BB*TOPK] = 320,000 (ends 400,256)
#define HIST_OFF   400256u      // uint[BB*NB]
#define START_OFF  465792u      // uint[BB*NB]
#define CNT_OFF    531328u      // uint[BB*NB]
#define GIDX_OFF   596864u      // uint[BB*PP]
#define GSC_OFF    1121152u     // float[BB*PP] (ends 1,645,440)
#define BM_OFF     400256u      // uint[2*TRIW] = 3,294,976 (ends 3,695,232)
#define WS_NEEDED  3742720u

// packed row start (words): toff(r) = 160r - 16q(q-1) - (r&31)q, q=r>>5.
// Row r stores original words [q,160): original word w at toff(r)+(w-q).
__device__ __forceinline__ unsigned toffw(unsigned r) {
    unsigned q = r >> 5, s = r & 31u;
    return r * 160u - 16u * q * (q - 1u) - s * q;
}

__global__ __launch_bounds__(256) void score_hist_kernel(
    const float2* __restrict__ conf, unsigned* __restrict__ hist)
{
    int i = blockIdx.x * 256 + threadIdx.x;
    if (i >= BB * PP) return;
    int b = i >> 15;
    float s = conf[i].y;
    if (s > 0.05f) {
        int bk = (int)(s * 4096.0f);
        bk = bk < 0 ? 0 : (bk > NB - 1 ? NB - 1 : bk);
        atomicAdd(&hist[b * NB + bk], 1u);
    }
}

__global__ __launch_bounds__(256) void scan_hist_kernel(
    const unsigned* __restrict__ hist, unsigned* __restrict__ start,
    int* __restrict__ nvalid, int* __restrict__ ncand)
{
    int b = blockIdx.x;
    int t = threadIdx.x;
    __shared__ unsigned sums[256];
    unsigned local[16];
    unsigned s = 0;
    const unsigned* hb = hist + b * NB;
    #pragma unroll
    for (int k = 0; k < 16; k++) {
        unsigned v = hb[t * 16 + k];
        local[k] = s;
        s += v;
    }
    sums[t] = s;
    __syncthreads();
    for (int off = 1; off < 256; off <<= 1) {
        unsigned v = (t >= off) ? sums[t - off] : 0u;
        __syncthreads();
        sums[t] += v;
        __syncthreads();
    }
    unsigned excl = sums[t] - s;
    unsigned* sb = start + b * NB;
    #pragma unroll
    for (int k = 0; k < 16; k++) sb[t * 16 + k] = excl + local[k];
    if (t == 255) {
        nvalid[b] = (int)sums[255];
        ncand[b] = sums[255] < (unsigned)TOPK ? (int)sums[255] : TOPK;
    }
}

__global__ __launch_bounds__(256) void scatter_group_kernel(
    const float2* __restrict__ conf, const unsigned* __restrict__ start,
    unsigned* __restrict__ cnt, unsigned* __restrict__ gidx,
    float* __restrict__ gscore)
{
    int i = blockIdx.x * 256 + threadIdx.x;
    if (i >= BB * PP) return;
    int b = i >> 15;
    int p = i & (PP - 1);
    float s = conf[i].y;
    if (s > 0.05f) {
        int bk = (int)(s * 4096.0f);
        bk = bk < 0 ? 0 : (bk > NB - 1 ? NB - 1 : bk);
        unsigned o = atomicAdd(&cnt[b * NB + bk], 1u);
        unsigned pos = start[b * NB + bk] + o;
        gidx[b * PP + pos] = (unsigned)p;
        gscore[b * PP + pos] = s;
    }
}

__global__ __launch_bounds__(256) void rank_topk_kernel(
    const unsigned* __restrict__ gidx, const float* __restrict__ gscore,
    const unsigned* __restrict__ start, const unsigned* __restrict__ hist,
    const int* __restrict__ nvalid, const float4* __restrict__ loc,
    const float4* __restrict__ prior,
    float* __restrict__ cs, float4* __restrict__ cb)
{
#pragma clang fp contract(off)
    int i = blockIdx.x * 256 + threadIdx.x;
    if (i >= BB * PP) return;
    int b = i >> 15;
    int pos = i & (PP - 1);
    int nv = nvalid[b];
    if (pos >= nv) return;
    float s = gscore[b * PP + pos];
    unsigned p = gidx[b * PP + pos];
    int bk = (int)(s * 4096.0f);
    bk = bk < 0 ? 0 : (bk > NB - 1 ? NB - 1 : bk);
    unsigned st = start[b * NB + bk];
    unsigned c = hist[b * NB + bk];
    unsigned rank = (unsigned)nv - st - c;
    const float* gs = gscore + b * PP + st;
    const unsigned* gi = gidx + b * PP + st;
    for (unsigned k = 0; k < c; k++) {
        float sk = gs[k];
        unsigned pk = gi[k];
        if (sk > s || (sk == s && pk < p)) rank++;
    }
    if (rank < (unsigned)TOPK) {
        float4 l = loc[b * PP + (int)p];
        float4 pr = prior[p];
        float cx = pr.x + (l.x * 0.1f) * pr.z;
        float cy = pr.y + (l.y * 0.1f) * pr.w;
        float w = pr.z * expf(l.z * 0.2f);
        float h = pr.w * expf(l.w * 0.2f);
        float4 bx;
        bx.x = cx - 0.5f * w;
        bx.y = cy - 0.5f * h;
        bx.z = cx + 0.5f * w;
        bx.w = cy + 0.5f * h;
        cs[b * TOPK + rank] = s;
        cb[(size_t)b * TOPK + rank] = bx;
    }
}

// Suppressor-major PACKED bitmap, two images per launch (p = blockIdx/TBPI).
// Row r: bit i (i>r) iff IoU(r,i)>0.3 — exact reference fp ops (proven r7-r12).
__global__ __launch_bounds__(256) void bitmap_pair_kernel(
    const float4* __restrict__ cb, int img_base, unsigned* __restrict__ bitmap)
{
#pragma clang fp contract(off)
    int p = blockIdx.x / TBPI;
    int t_ = blockIdx.x % TBPI;
    int img = img_base + p;
    unsigned* bmp = bitmap + (size_t)p * TRIW;

    int bi = (int)((sqrtf(8.0f * (float)t_ + 1.0f) - 1.0f) * 0.5f);
    while ((bi + 1) * (bi + 2) / 2 <= t_) bi++;
    while (bi * (bi + 1) / 2 > t_) bi--;
    int bj = t_ - bi * (bi + 1) / 2;

    const float4* cbb = cb + (size_t)img * TOPK;

    __shared__ float4 jb[256];
    __shared__ float ja[256];
    int tid = threadIdx.x;
    int cg = bi * 256 + tid;
    if (cg < TOPK) {
        float4 v = cbb[cg];
        jb[tid] = v;
        ja[tid] = (v.z - v.x) * (v.w - v.y);
    }
    __syncthreads();

    int r = bj * 256 + tid;
    if (r >= TOPK) return;
    float4 bx = cbb[r];
    float areaR = (bx.z - bx.x) * (bx.w - bx.y);
    bool diag = (bi == bj);

    unsigned wds[8];
    #pragma unroll
    for (int w8 = 0; w8 < 8; w8++) {
        unsigned m = 0u;
        int cb0 = w8 * 32;
        for (int k = 0; k < 32; k++) {
            int cl = cb0 + k;
            int c = bi * 256 + cl;
            if (c >= TOPK) break;
            if (diag && c <= r) continue;      // strict upper triangle
            float4 cc = jb[cl];
            float iw = fminf(bx.z, cc.z) - fmaxf(bx.x, cc.x);
            iw = fmaxf(iw, 0.0f);
            float ih = fminf(bx.w, cc.w) - fmaxf(bx.y, cc.y);
            ih = fmaxf(ih, 0.0f);
            float inter = iw * ih;
            float uni = (ja[cl] + areaR) - inter;
            if (inter / uni > 0.3f) m |= (1u << k);
        }
        wds[w8] = m;
    }
    unsigned q = (unsigned)r >> 5;
    unsigned basew = toffw((unsigned)r) - q + 8u * (unsigned)bi;
    int c0 = diag ? (int)(q - 8u * (unsigned)bj) : 0;
    for (int c = c0; c < 8; c++) bmp[basew + (unsigned)c] = wds[c];
}

// SINGLE-WAVE register-direct greedy solve. No LDS ring, no producers, no
// in-loop barriers. Depth-3 prefetch over named register buffers (A,B,C);
// 16 dwordx4 loads/batch (48 outstanding <= 63); compiler-counted vmcnt.
// Diagonal word = packed word 0 of each row = shfl of loaded reg (q uniform
// per batch). Garbage in lane-words < q / clamped tail rows is provably
// masked (already-decided words; msk=0). Proven chain logic from r9-r12.
__global__ __launch_bounds__(64, 1) void solve_reg_kernel(
    const float* __restrict__ cs, const float4* __restrict__ cb,
    const int* __restrict__ ncand, int img_base,
    const unsigned* __restrict__ bitmap, float* __restrict__ out)
{
    int lane = threadIdx.x;
    int img = img_base + blockIdx.x;
    int nc = ncand[img];
    const unsigned* bm = bitmap + (size_t)blockIdx.x * TRIW;

    __shared__ unsigned kw[BMW];
    __shared__ unsigned pref[BMW];
    for (int w = lane; w < BMW; w += 64) kw[w] = 0u;
    __syncthreads();

    if (nc > 0) {
        unsigned R0, R1, R2, R3;
        {   // removed-mask init: bits i >= nc pre-removed
            unsigned m[4];
            #pragma unroll
            for (int q = 0; q < 4; q++) {
                int w = 4 * lane + q;
                int lo = w * 32;
                if (lo >= nc) m[q] = 0xffffffffu;
                else if (lo + 32 <= nc) m[q] = 0u;
                else m[q] = ~((1u << (nc - lo)) - 1u);
            }
            R0 = m[0]; R1 = m[1]; R2 = m[2]; R3 = m[3];
        }

        int nb = (nc + 15) >> 4;
        unsigned l4 = (unsigned)lane << 2;
        uint4 bufA[16], bufB[16], bufC[16];
        unsigned curW = 0u, keptW = 0u;

#define LOADB(BUF, KB) do {                                                \
    int kb_ = (KB);                                                        \
    if (kb_ < nb) {                                                        \
        _Pragma("unroll")                                                  \
        for (int jj = 0; jj < 16; jj++) {                                  \
            int j_ = kb_ * 16 + jj;                                        \
            unsigned jc_ = (unsigned)(j_ < nc ? j_ : nc - 1);              \
            unsigned q_ = jc_ >> 5;                                        \
            const unsigned* p_ = bm + (toffw(jc_) - q_ + l4);              \
            __builtin_memcpy(&BUF[jj], p_, 16);                            \
        }                                                                  \
    }                                                                      \
} while (0)

#define PROCB(BUF, KB) do {                                                \
    int kb_ = (KB);                                                        \
    if (kb_ < nb) {                                                        \
        int b0_ = kb_ << 4;                                                \
        unsigned q_ = (unsigned)b0_ >> 5;                                  \
        if ((b0_ & 31) == 0) {                                             \
            if (b0_ > 0 && lane == 0) kw[q_ - 1] = keptW;                  \
            keptW = 0u;                                                    \
            unsigned qq_ = q_ & 3u;                                        \
            unsigned Rs_ = qq_ == 0u ? R0 : qq_ == 1u ? R1                 \
                         : qq_ == 2u ? R2 : R3;                            \
            curW = __shfl(Rs_, (int)(q_ >> 2));                            \
        }                                                                  \
        int lsrc_ = (int)(q_ >> 2);                                        \
        unsigned qc_ = q_ & 3u;                                            \
        unsigned dia_[16];                                                 \
        _Pragma("unroll")                                                  \
        for (int jj = 0; jj < 16; jj++) {                                  \
            unsigned c_ = qc_ == 0u ? BUF[jj].x : qc_ == 1u ? BUF[jj].y    \
                        : qc_ == 2u ? BUF[jj].z : BUF[jj].w;               \
            dia_[jj] = __shfl(c_, lsrc_);                                  \
        }                                                                  \
        _Pragma("unroll")                                                  \
        for (int jj = 0; jj < 16; jj++) {                                  \
            int j_ = b0_ + jj;                                             \
            unsigned bit_ = (unsigned)j_ & 31u;                            \
            unsigned d_ = (curW >> bit_) & 1u;                             \
            unsigned msk_ = d_ - 1u;            /* ~0 if alive, 0 if dead */\
            curW |= dia_[jj] & msk_;                                       \
            keptW |= (d_ ^ 1u) << bit_;                                    \
            R0 |= BUF[jj].x & msk_;                                        \
            R1 |= BUF[jj].y & msk_;                                        \
            R2 |= BUF[jj].z & msk_;                                        \
            R3 |= BUF[jj].w & msk_;                                        \
        }                                                                  \
    }                                                                      \
} while (0)

        LOADB(bufA, 0);
        LOADB(bufB, 1);
        LOADB(bufC, 2);
        for (int k = 0; k < nb; k += 3) {
            PROCB(bufA, k);     LOADB(bufA, k + 3);
            PROCB(bufB, k + 1); LOADB(bufB, k + 4);
            PROCB(bufC, k + 2); LOADB(bufC, k + 5);
        }
#undef LOADB
#undef PROCB
        if (lane == 0) kw[(unsigned)(nc - 1) >> 5] = keptW;
    }
    __syncthreads();
    if (lane == 0) {
        unsigned s = 0;
        for (int w = 0; w < BMW; w++) { pref[w] = s; s += __popc(kw[w]); }
    }
    __syncthreads();

    const float* csb = cs + img * TOPK;
    const float4* cbb = cb + (size_t)img * TOPK;
    float* outb = out + ((size_t)img * 2 + 1) * TOPK * 5;
    for (int i = lane; i < nc; i += 64) {
        unsigned w = kw[i >> 5];
        if ((w >> (i & 31)) & 1u) {
            unsigned pos = pref[i >> 5] + __popc(w & ((1u << (i & 31)) - 1u));
            float4 bx = cbb[i];
            float* row = outb + (size_t)pos * 5;
            row[0] = csb[i];
            row[1] = bx.x;
            row[2] = bx.y;
            row[3] = bx.z;
            row[4] = bx.w;
        }
    }
}

extern "C" void kernel_launch(void* const* d_in, const int* in_sizes, int n_in,
                              void* d_out, int out_size, void* d_ws, size_t ws_size,
                              hipStream_t stream) {
    if (ws_size < WS_NEEDED) return;  // fail loudly rather than corrupt

    const float4* loc = (const float4*)d_in[0];
    const float2* conf = (const float2*)d_in[1];
    const float4* prior = (const float4*)d_in[2];
    float* out = (float*)d_out;

    char* ws = (char*)d_ws;
    int* nvalid = (int*)(ws + NV_OFF);
    int* ncand = (int*)(ws + NC_OFF);
    float* cs = (float*)(ws + CS_OFF);
    float4* cb = (float4*)(ws + CB_OFF);
    unsigned* hist = (unsigned*)(ws + HIST_OFF);
    unsigned* start = (unsigned*)(ws + START_OFF);
    unsigned* cnt = (unsigned*)(ws + CNT_OFF);
    unsigned* gidx = (unsigned*)(ws + GIDX_OFF);
    float* gscore = (float*)(ws + GSC_OFF);
    unsigned* bitmap = (unsigned*)(ws + BM_OFF);  // 2 packed images

    hipMemsetAsync(d_out, 0, (size_t)out_size * sizeof(float), stream);
    hipMemsetAsync(hist, 0, (size_t)BB * NB * sizeof(unsigned), stream);
    hipMemsetAsync(cnt, 0, (size_t)BB * NB * sizeof(unsigned), stream);

    int nblk = (BB * PP + 255) / 256;
    score_hist_kernel<<<nblk, 256, 0, stream>>>(conf, hist);
    scan_hist_kernel<<<BB, 256, 0, stream>>>(hist, start, nvalid, ncand);
    scatter_group_kernel<<<nblk, 256, 0, stream>>>(conf, start, cnt, gidx, gscore);
    rank_topk_kernel<<<nblk, 256, 0, stream>>>(gidx, gscore, start, hist, nvalid,
                                               loc, prior, cs, cb);
    for (int g = 0; g < 2; ++g) {
        bitmap_pair_kernel<<<2 * TBPI, 256, 0, stream>>>(cb, 2 * g, bitmap);
        solve_reg_kernel<<<2, 64, 0, stream>>>(cs, cb, ncand, 2 * g, bitmap, out);
    }
}

// Round 14
// 484.088 us; speedup vs baseline: 2.5178x; 2.5178x over previous
//
#include <hip/hip_runtime.h>
#include <hip/hip_bf16.h>
#include <math.h>

// Problem constants (match reference)
#define BB 4
#define PP 32768
#define TOPK 5000
#define NB 4096
#define NBK 20
#define TBPI 210         // NBK*(NBK+1)/2 triangular tile pairs
#define BMW 160          // bitmap words per (full) row
#define TRIW 411872u     // packed triangular bitmap words per image

// ws layout (bytes). End 3,695,232 (+<=1KB read overrun) <= 3,742,720 proven.
#define NV_OFF     0u
#define NC_OFF     64u
#define CS_OFF     256u         // float[BB*TOPK]  = 80,000
#define CB_OFF     80256u       // float4[BB*TOPK] = 320,000 (ends 400,256)
#define HIST_OFF   400256u      // uint[BB*NB]
#define START_OFF  465792u      // uint[BB*NB]
#define CNT_OFF    531328u      // uint[BB*NB]
#define GIDX_OFF   596864u      // uint[BB*PP]
#define GSC_OFF    1121152u     // float[BB*PP] (ends 1,645,440)
#define BM_OFF     400256u      // uint[2*TRIW] = 3,294,976 (ends 3,695,232)
#define WS_NEEDED  3742720u

// packed row start (words): toff(r) = 160r - 16q(q-1) - (r&31)q, q=r>>5.
// Row r stores original words [q,160): original word w at toff(r)+(w-q).
__device__ __forceinline__ unsigned toffw(unsigned r) {
    unsigned q = r >> 5, s = r & 31u;
    return r * 160u - 16u * q * (q - 1u) - s * q;
}

__global__ __launch_bounds__(256) void score_hist_kernel(
    const float2* __restrict__ conf, unsigned* __restrict__ hist)
{
    int i = blockIdx.x * 256 + threadIdx.x;
    if (i >= BB * PP) return;
    int b = i >> 15;
    float s = conf[i].y;
    if (s > 0.05f) {
        int bk = (int)(s * 4096.0f);
        bk = bk < 0 ? 0 : (bk > NB - 1 ? NB - 1 : bk);
        atomicAdd(&hist[b * NB + bk], 1u);
    }
}

__global__ __launch_bounds__(256) void scan_hist_kernel(
    const unsigned* __restrict__ hist, unsigned* __restrict__ start,
    int* __restrict__ nvalid, int* __restrict__ ncand)
{
    int b = blockIdx.x;
    int t = threadIdx.x;
    __shared__ unsigned sums[256];
    unsigned local[16];
    unsigned s = 0;
    const unsigned* hb = hist + b * NB;
    #pragma unroll
    for (int k = 0; k < 16; k++) {
        unsigned v = hb[t * 16 + k];
        local[k] = s;
        s += v;
    }
    sums[t] = s;
    __syncthreads();
    for (int off = 1; off < 256; off <<= 1) {
        unsigned v = (t >= off) ? sums[t - off] : 0u;
        __syncthreads();
        sums[t] += v;
        __syncthreads();
    }
    unsigned excl = sums[t] - s;
    unsigned* sb = start + b * NB;
    #pragma unroll
    for (int k = 0; k < 16; k++) sb[t * 16 + k] = excl + local[k];
    if (t == 255) {
        nvalid[b] = (int)sums[255];
        ncand[b] = sums[255] < (unsigned)TOPK ? (int)sums[255] : TOPK;
    }
}

__global__ __launch_bounds__(256) void scatter_group_kernel(
    const float2* __restrict__ conf, const unsigned* __restrict__ start,
    unsigned* __restrict__ cnt, unsigned* __restrict__ gidx,
    float* __restrict__ gscore)
{
    int i = blockIdx.x * 256 + threadIdx.x;
    if (i >= BB * PP) return;
    int b = i >> 15;
    int p = i & (PP - 1);
    float s = conf[i].y;
    if (s > 0.05f) {
        int bk = (int)(s * 4096.0f);
        bk = bk < 0 ? 0 : (bk > NB - 1 ? NB - 1 : bk);
        unsigned o = atomicAdd(&cnt[b * NB + bk], 1u);
        unsigned pos = start[b * NB + bk] + o;
        gidx[b * PP + pos] = (unsigned)p;
        gscore[b * PP + pos] = s;
    }
}

__global__ __launch_bounds__(256) void rank_topk_kernel(
    const unsigned* __restrict__ gidx, const float* __restrict__ gscore,
    const unsigned* __restrict__ start, const unsigned* __restrict__ hist,
    const int* __restrict__ nvalid, const float4* __restrict__ loc,
    const float4* __restrict__ prior,
    float* __restrict__ cs, float4* __restrict__ cb)
{
#pragma clang fp contract(off)
    int i = blockIdx.x * 256 + threadIdx.x;
    if (i >= BB * PP) return;
    int b = i >> 15;
    int pos = i & (PP - 1);
    int nv = nvalid[b];
    if (pos >= nv) return;
    float s = gscore[b * PP + pos];
    unsigned p = gidx[b * PP + pos];
    int bk = (int)(s * 4096.0f);
    bk = bk < 0 ? 0 : (bk > NB - 1 ? NB - 1 : bk);
    unsigned st = start[b * NB + bk];
    unsigned c = hist[b * NB + bk];
    unsigned rank = (unsigned)nv - st - c;
    const float* gs = gscore + b * PP + st;
    const unsigned* gi = gidx + b * PP + st;
    for (unsigned k = 0; k < c; k++) {
        float sk = gs[k];
        unsigned pk = gi[k];
        if (sk > s || (sk == s && pk < p)) rank++;
    }
    if (rank < (unsigned)TOPK) {
        float4 l = loc[b * PP + (int)p];
        float4 pr = prior[p];
        float cx = pr.x + (l.x * 0.1f) * pr.z;
        float cy = pr.y + (l.y * 0.1f) * pr.w;
        float w = pr.z * expf(l.z * 0.2f);
        float h = pr.w * expf(l.w * 0.2f);
        float4 bx;
        bx.x = cx - 0.5f * w;
        bx.y = cy - 0.5f * h;
        bx.z = cx + 0.5f * w;
        bx.w = cy + 0.5f * h;
        cs[b * TOPK + rank] = s;
        cb[(size_t)b * TOPK + rank] = bx;
    }
}

// Suppressor-major PACKED bitmap, two images per launch. Proven r7-r13.
__global__ __launch_bounds__(256) void bitmap_pair_kernel(
    const float4* __restrict__ cb, int img_base, unsigned* __restrict__ bitmap)
{
#pragma clang fp contract(off)
    int p = blockIdx.x / TBPI;
    int t_ = blockIdx.x % TBPI;
    int img = img_base + p;
    unsigned* bmp = bitmap + (size_t)p * TRIW;

    int bi = (int)((sqrtf(8.0f * (float)t_ + 1.0f) - 1.0f) * 0.5f);
    while ((bi + 1) * (bi + 2) / 2 <= t_) bi++;
    while (bi * (bi + 1) / 2 > t_) bi--;
    int bj = t_ - bi * (bi + 1) / 2;

    const float4* cbb = cb + (size_t)img * TOPK;

    __shared__ float4 jb[256];
    __shared__ float ja[256];
    int tid = threadIdx.x;
    int cg = bi * 256 + tid;
    if (cg < TOPK) {
        float4 v = cbb[cg];
        jb[tid] = v;
        ja[tid] = (v.z - v.x) * (v.w - v.y);
    }
    __syncthreads();

    int r = bj * 256 + tid;
    if (r >= TOPK) return;
    float4 bx = cbb[r];
    float areaR = (bx.z - bx.x) * (bx.w - bx.y);
    bool diag = (bi == bj);

    unsigned wds[8];
    #pragma unroll
    for (int w8 = 0; w8 < 8; w8++) {
        unsigned m = 0u;
        int cb0 = w8 * 32;
        for (int k = 0; k < 32; k++) {
            int cl = cb0 + k;
            int c = bi * 256 + cl;
            if (c >= TOPK) break;
            if (diag && c <= r) continue;      // strict upper triangle
            float4 cc = jb[cl];
            float iw = fminf(bx.z, cc.z) - fmaxf(bx.x, cc.x);
            iw = fmaxf(iw, 0.0f);
            float ih = fminf(bx.w, cc.w) - fmaxf(bx.y, cc.y);
            ih = fmaxf(ih, 0.0f);
            float inter = iw * ih;
            float uni = (ja[cl] + areaR) - inter;
            if (inter / uni > 0.3f) m |= (1u << k);
        }
        wds[w8] = m;
    }
    unsigned q = (unsigned)r >> 5;
    unsigned basew = toffw((unsigned)r) - q + 8u * (unsigned)bi;
    int c0 = diag ? (int)(q - 8u * (unsigned)bj) : 0;
    for (int c = c0; c < 8; c++) bmp[basew + (unsigned)c] = wds[c];
}

// DECIDE/FOLD solve: 9 waves. Wave 0 = serial greedy decide per 32-cand word
// using ONLY 32 diagonal words (4B/row on-chain). Waves 1-8 = lazy fold: each
// holds 4 rows x uint4 in regs, masks by kept-word, atomicOr into LDS removed
// mask Rl[160]. Invariant: at decide(w), Rl[w] = init | OR_{kept j<32w} row_j[w].
// Raw lgkmcnt+s_barrier (no vmcnt drain); loads have >=1 iteration of lead.
// Garbage from packed under-reads lands only in words < w (already decided).
__global__ __launch_bounds__(576, 1) void solve_fold_kernel(
    const float* __restrict__ cs, const float4* __restrict__ cb,
    const int* __restrict__ ncand, int img_base,
    const unsigned* __restrict__ bitmap, float* __restrict__ out)
{
    int tid = threadIdx.x;
    int wv = tid >> 6;
    int lane = tid & 63;
    int img = img_base + blockIdx.x;
    int nc = ncand[img];
    const unsigned* bm = bitmap + (size_t)blockIdx.x * TRIW;

    __shared__ unsigned Rl[BMW];
    __shared__ __align__(16) unsigned diab[2][32];
    __shared__ unsigned kw[BMW];
    __shared__ unsigned pref[BMW];

    for (int w = tid; w < BMW; w += 576) {
        kw[w] = 0u;
        int lo = w * 32;
        unsigned m;
        if (lo >= nc) m = 0xffffffffu;
        else if (lo + 32 <= nc) m = 0u;
        else m = ~((1u << (nc - lo)) - 1u);
        Rl[w] = m;
    }

    int ng = (nc + 31) >> 5;
    unsigned l4 = (unsigned)lane << 2;
    uint4 P0[4], P1[4];

#define LOADG(BUF, G) do {                                                  \
    int g_ = (G);                                                           \
    if (g_ < ng) {                                                          \
        _Pragma("unroll")                                                   \
        for (int rr = 0; rr < 4; rr++) {                                    \
            int j_ = g_ * 32 + (wv - 1) + 8 * rr;                           \
            unsigned jc_ = (unsigned)(j_ < nc ? j_ : nc - 1);               \
            unsigned q_ = jc_ >> 5;                                         \
            const unsigned* p_ = bm + (toffw(jc_) - q_ + l4);               \
            BUF[rr].x = p_[0]; BUF[rr].y = p_[1];                           \
            BUF[rr].z = p_[2]; BUF[rr].w = p_[3];                           \
        }                                                                   \
    }                                                                       \
} while (0)

#define DECIDE(W, PAR) do {                                                 \
    int w_ = (W);                                                           \
    unsigned rW_ = Rl[w_];                                                  \
    unsigned d_[32];                                                        \
    _Pragma("unroll")                                                       \
    for (int k8_ = 0; k8_ < 8; k8_++)                                       \
        *(uint4*)&d_[4 * k8_] = *(const uint4*)&diab[PAR][4 * k8_];         \
    unsigned curW_ = rW_, keptW_ = 0u;                                      \
    _Pragma("unroll")                                                       \
    for (int jj = 0; jj < 32; jj++) {                                       \
        unsigned al_ = ((curW_ >> jj) & 1u) ^ 1u;                           \
        unsigned m_ = 0u - al_;                                             \
        curW_ |= d_[jj] & m_;                                               \
        keptW_ |= al_ << jj;                                                \
    }                                                                       \
    if (lane == 0) kw[w_] = keptW_;                                         \
} while (0)

#define FOLDG(OWN, OTHER, W) do {                                           \
    int w_ = (W);                                                           \
    unsigned kwv_ = kw[w_];                                                 \
    uint4 acc_; acc_.x = acc_.y = acc_.z = acc_.w = 0u;                     \
    _Pragma("unroll")                                                       \
    for (int rr = 0; rr < 4; rr++) {                                        \
        int r_ = (wv - 1) + 8 * rr;                                         \
        unsigned a_ = (kwv_ >> r_) & 1u;                                    \
        unsigned m_ = 0u - a_;                                              \
        acc_.x |= OWN[rr].x & m_; acc_.y |= OWN[rr].y & m_;                 \
        acc_.z |= OWN[rr].z & m_; acc_.w |= OWN[rr].w & m_;                 \
    }                                                                       \
    if (lane < 40) {                                                        \
        if (acc_.x) atomicOr(&Rl[l4 + 0], acc_.x);                          \
        if (acc_.y) atomicOr(&Rl[l4 + 1], acc_.y);                          \
        if (acc_.z) atomicOr(&Rl[l4 + 2], acc_.z);                          \
        if (acc_.w) atomicOr(&Rl[l4 + 3], acc_.w);                          \
    }                                                                       \
    int wn_ = w_ + 1;                                                       \
    if (wn_ < ng) {                                                         \
        if (lane == (wn_ >> 2)) {                                           \
            unsigned c_ = (unsigned)wn_ & 3u;                               \
            _Pragma("unroll")                                               \
            for (int rr = 0; rr < 4; rr++) {                                \
                unsigned dv_ = c_ == 0u ? OTHER[rr].x                       \
                             : c_ == 1u ? OTHER[rr].y                       \
                             : c_ == 2u ? OTHER[rr].z : OTHER[rr].w;        \
                diab[wn_ & 1][(wv - 1) + 8 * rr] = dv_;                     \
            }                                                               \
        }                                                                   \
    }                                                                       \
    LOADG(OWN, w_ + 2);                                                     \
} while (0)

#define RBAR do {                                                           \
    asm volatile("s_waitcnt lgkmcnt(0)" ::: "memory");                      \
    __builtin_amdgcn_s_barrier();                                           \
} while (0)

    if (wv > 0) {
        LOADG(P0, 0);
        LOADG(P1, 1);
        if (ng > 0 && lane == 0) {   // dia of group 0 = word 0 = comp x of lane 0
            #pragma unroll
            for (int rr = 0; rr < 4; rr++)
                diab[0][(wv - 1) + 8 * rr] = P0[rr].x;
        }
    }
    __syncthreads();

    for (int w = 0; w < ng; w += 2) {
        RBAR;
        if (wv == 0) DECIDE(w, 0);
        RBAR;
        if (wv > 0) FOLDG(P0, P1, w);
        if (w + 1 < ng) {
            RBAR;
            if (wv == 0) DECIDE(w + 1, 1);
            RBAR;
            if (wv > 0) FOLDG(P1, P0, w + 1);
        }
    }
#undef LOADG
#undef DECIDE
#undef FOLDG
#undef RBAR

    __syncthreads();
    if (tid == 0) {
        unsigned s = 0;
        for (int w = 0; w < BMW; w++) { pref[w] = s; s += __popc(kw[w]); }
    }
    __syncthreads();

    const float* csb = cs + img * TOPK;
    const float4* cbb = cb + (size_t)img * TOPK;
    float* outb = out + ((size_t)img * 2 + 1) * TOPK * 5;
    for (int i = tid; i < nc; i += 576) {
        unsigned w = kw[i >> 5];
        if ((w >> (i & 31)) & 1u) {
            unsigned pos = pref[i >> 5] + __popc(w & ((1u << (i & 31)) - 1u));
            float4 bx = cbb[i];
            float* row = outb + (size_t)pos * 5;
            row[0] = csb[i];
            row[1] = bx.x;
            row[2] = bx.y;
            row[3] = bx.z;
            row[4] = bx.w;
        }
    }
}

extern "C" void kernel_launch(void* const* d_in, const int* in_sizes, int n_in,
                              void* d_out, int out_size, void* d_ws, size_t ws_size,
                              hipStream_t stream) {
    if (ws_size < WS_NEEDED) return;  // fail loudly rather than corrupt

    const float4* loc = (const float4*)d_in[0];
    const float2* conf = (const float2*)d_in[1];
    const float4* prior = (const float4*)d_in[2];
    float* out = (float*)d_out;

    char* ws = (char*)d_ws;
    int* nvalid = (int*)(ws + NV_OFF);
    int* ncand = (int*)(ws + NC_OFF);
    float* cs = (float*)(ws + CS_OFF);
    float4* cb = (float4*)(ws + CB_OFF);
    unsigned* hist = (unsigned*)(ws + HIST_OFF);
    unsigned* start = (unsigned*)(ws + START_OFF);
    unsigned* cnt = (unsigned*)(ws + CNT_OFF);
    unsigned* gidx = (unsigned*)(ws + GIDX_OFF);
    float* gscore = (float*)(ws + GSC_OFF);
    unsigned* bitmap = (unsigned*)(ws + BM_OFF);  // 2 packed images

    hipMemsetAsync(d_out, 0, (size_t)out_size * sizeof(float), stream);
    hipMemsetAsync(hist, 0, (size_t)BB * NB * sizeof(unsigned), stream);
    hipMemsetAsync(cnt, 0, (size_t)BB * NB * sizeof(unsigned), stream);

    int nblk = (BB * PP + 255) / 256;
    score_hist_kernel<<<nblk, 256, 0, stream>>>(conf, hist);
    scan_hist_kernel<<<BB, 256, 0, stream>>>(hist, start, nvalid, ncand);
    scatter_group_kernel<<<nblk, 256, 0, stream>>>(conf, start, cnt, gidx, gscore);
    rank_topk_kernel<<<nblk, 256, 0, stream>>>(gidx, gscore, start, hist, nvalid,
                                               loc, prior, cs, cb);
    for (int g = 0; g < 2; ++g) {
        bitmap_pair_kernel<<<2 * TBPI, 256, 0, stream>>>(cb, 2 * g, bitmap);
        solve_fold_kernel<<<2, 576, 0, stream>>>(cs, cb, ncand, 2 * g, bitmap, out);
    }
}